// Round 3
// baseline (1973.140 us; speedup 1.0000x reference)
//
#include <hip/hip_runtime.h>
#include <hip/hip_bf16.h>

// SNN: B=128, T=16, IN=2048, HID=2048, OUT=1024; 16 outer x 16 inner = 256 steps.
//   Z1 = X @ W1^T + b1               (one GEMM; x repeats across outer iters)
//   S1[tau] spikes: per-(b,h) recurrence, bit-packed via __ballot (8.4 MB)
//   Z2 = S1 @ W2^T + b2              chunked over tau (4 x 64 steps, 33.5 MB buf)
//   out = per-(b,o) recurrence over Z2, counting spikes for tau >= 240
// Workspace budget kept under ~60 MB in case ws_size is small (suspected cause
// of the container wedge: previous layout assumed 285 MB of d_ws unchecked).
constexpr int B   = 128;
constexpr int T   = 16;
constexpr int IN  = 2048;
constexpr int HID = 2048;
constexpr int OUT = 1024;
constexpr int TAU = 256;
constexpr int CHUNK = 64;              // tau steps per GEMM2/rec2 chunk
constexpr float DECAY  = 0.2f;
constexpr float THRESH = 0.5f;

// ---------------- GEMM1: C[M][N] = A[M][K] @ W[N][K]^T + bias, all fp32 ----
__global__ __launch_bounds__(256)
void gemm1_f32(const float* __restrict__ A, const float* __restrict__ W,
               const float* __restrict__ bias, float* __restrict__ C,
               int M, int N, int K)
{
    __shared__ float As[8][128];
    __shared__ float Bs[8][128];
    const int tid = threadIdx.x;
    const int tx = tid & 15, ty = tid >> 4;
    const int row0 = blockIdx.y * 128, col0 = blockIdx.x * 128;

    float acc[8][8];
    #pragma unroll
    for (int i = 0; i < 8; i++)
        #pragma unroll
        for (int j = 0; j < 8; j++) acc[i][j] = 0.f;

    const int sr = tid >> 1;          // tile row 0..127
    const int sk = (tid & 1) << 2;    // k sub-offset 0 or 4

    for (int k0 = 0; k0 < K; k0 += 8) {
        float4 av = *(const float4*)(A + (size_t)(row0 + sr) * K + (k0 + sk));
        float4 bv = *(const float4*)(W + (size_t)(col0 + sr) * K + (k0 + sk));
        __syncthreads();
        As[sk + 0][sr] = av.x; As[sk + 1][sr] = av.y;
        As[sk + 2][sr] = av.z; As[sk + 3][sr] = av.w;
        Bs[sk + 0][sr] = bv.x; Bs[sk + 1][sr] = bv.y;
        Bs[sk + 2][sr] = bv.z; Bs[sk + 3][sr] = bv.w;
        __syncthreads();
        #pragma unroll
        for (int k = 0; k < 8; k++) {
            float a[8], b[8];
            #pragma unroll
            for (int i = 0; i < 8; i++) a[i] = As[k][ty * 8 + i];
            #pragma unroll
            for (int j = 0; j < 8; j++) b[j] = Bs[k][tx * 8 + j];
            #pragma unroll
            for (int i = 0; i < 8; i++)
                #pragma unroll
                for (int j = 0; j < 8; j++)
                    acc[i][j] = fmaf(a[i], b[j], acc[i][j]);
        }
    }
    #pragma unroll
    for (int i = 0; i < 8; i++) {
        size_t r = (size_t)(row0 + ty * 8 + i);
        int c0 = col0 + tx * 8;
        float4 o0, o1;
        o0.x = acc[i][0] + bias[c0 + 0]; o0.y = acc[i][1] + bias[c0 + 1];
        o0.z = acc[i][2] + bias[c0 + 2]; o0.w = acc[i][3] + bias[c0 + 3];
        o1.x = acc[i][4] + bias[c0 + 4]; o1.y = acc[i][5] + bias[c0 + 5];
        o1.z = acc[i][6] + bias[c0 + 6]; o1.w = acc[i][7] + bias[c0 + 7];
        *(float4*)(C + r * N + c0)     = o0;
        *(float4*)(C + r * N + c0 + 4) = o1;
    }
}

// ---------------- rec1: layer-1 recurrence, bit-packed spike output --------
// One thread per (b,h); wave = 64 consecutive h. Sbits layout: [tau][b][h/64]
// u64 words (little-endian byte j of word = h%64 in [8j, 8j+8)).
__global__ __launch_bounds__(256)
void rec1(const float* __restrict__ Z1, unsigned long long* __restrict__ Sbits)
{
    int idx = blockIdx.x * 256 + threadIdx.x;   // b*HID + h
    int h = idx & (HID - 1);
    int b = idx >> 11;
    float z[16];
    #pragma unroll
    for (int t = 0; t < 16; t++)
        z[t] = Z1[((size_t)(b * T + t)) * HID + h];
    const size_t wbase = (size_t)b * (HID / 64) + (h >> 6);
    const bool lead = (threadIdx.x & 63) == 0;
    float m = 0.f, s = 0.f;
    for (int tau = 0; tau < TAU; ++tau) {
        m = m * DECAY * (1.f - s) + z[tau & 15];
        unsigned long long mask = __ballot(m > THRESH);
        s = (m > THRESH) ? 1.f : 0.f;
        if (lead)
            Sbits[(size_t)tau * (B * HID / 64) + wbase] = mask;
    }
}

// ---------------- GEMM2 chunk: Z2c = S1(bits) @ W2^T + b2 ------------------
// A rows are global spike rows m = tau*B + b, bytes Sbytes[m*256 + k/8].
__global__ __launch_bounds__(256)
void gemm2_bits(const unsigned char* __restrict__ Sbytes,
                const float* __restrict__ W, const float* __restrict__ bias,
                float* __restrict__ C, int m0glob)
{
    __shared__ float As[8][128];
    __shared__ float Bs[8][128];
    const int tid = threadIdx.x;
    const int tx = tid & 15, ty = tid >> 4;
    const int row0 = blockIdx.y * 128, col0 = blockIdx.x * 128;
    const int K = HID, N = OUT;

    float acc[8][8];
    #pragma unroll
    for (int i = 0; i < 8; i++)
        #pragma unroll
        for (int j = 0; j < 8; j++) acc[i][j] = 0.f;

    const int sr = tid >> 1;
    const int sk = (tid & 1) << 2;
    const size_t arow = (size_t)(m0glob + row0 + sr) * (K / 8);

    for (int k0 = 0; k0 < K; k0 += 8) {
        unsigned int byte = Sbytes[arow + (k0 >> 3)];
        float4 bv = *(const float4*)(W + (size_t)(col0 + sr) * K + (k0 + sk));
        __syncthreads();
        As[sk + 0][sr] = (float)((byte >> (sk + 0)) & 1u);
        As[sk + 1][sr] = (float)((byte >> (sk + 1)) & 1u);
        As[sk + 2][sr] = (float)((byte >> (sk + 2)) & 1u);
        As[sk + 3][sr] = (float)((byte >> (sk + 3)) & 1u);
        Bs[sk + 0][sr] = bv.x; Bs[sk + 1][sr] = bv.y;
        Bs[sk + 2][sr] = bv.z; Bs[sk + 3][sr] = bv.w;
        __syncthreads();
        #pragma unroll
        for (int k = 0; k < 8; k++) {
            float a[8], b[8];
            #pragma unroll
            for (int i = 0; i < 8; i++) a[i] = As[k][ty * 8 + i];
            #pragma unroll
            for (int j = 0; j < 8; j++) b[j] = Bs[k][tx * 8 + j];
            #pragma unroll
            for (int i = 0; i < 8; i++)
                #pragma unroll
                for (int j = 0; j < 8; j++)
                    acc[i][j] = fmaf(a[i], b[j], acc[i][j]);
        }
    }
    #pragma unroll
    for (int i = 0; i < 8; i++) {
        size_t r = (size_t)(row0 + ty * 8 + i);
        int c0 = col0 + tx * 8;
        float4 o0, o1;
        o0.x = acc[i][0] + bias[c0 + 0]; o0.y = acc[i][1] + bias[c0 + 1];
        o0.z = acc[i][2] + bias[c0 + 2]; o0.w = acc[i][3] + bias[c0 + 3];
        o1.x = acc[i][4] + bias[c0 + 4]; o1.y = acc[i][5] + bias[c0 + 5];
        o1.z = acc[i][6] + bias[c0 + 6]; o1.w = acc[i][7] + bias[c0 + 7];
        *(float4*)(C + r * N + c0)     = o0;
        *(float4*)(C + r * N + c0 + 4) = o1;
    }
}

// ---------------- rec2 chunk: layer-2 recurrence over 64 tau steps ---------
__global__ __launch_bounds__(256)
void rec2_chunk(const float* __restrict__ Z2c, float* __restrict__ m_state,
                float* __restrict__ s_state, float* __restrict__ out,
                int tau0, int last)
{
    int idx = blockIdx.x * 256 + threadIdx.x;   // b*OUT + o
    int o = idx & (OUT - 1);
    int b = idx >> 10;
    float m, s;
    if (tau0 == 0) { m = 0.f; s = 0.f; }
    else           { m = m_state[idx]; s = s_state[idx]; }
    float acc = 0.f;
    for (int tl = 0; tl < CHUNK; ++tl) {
        float zv = Z2c[((size_t)(tl * B + b)) * OUT + o];
        m = m * DECAY * (1.f - s) + zv;
        s = (m > THRESH) ? 1.f : 0.f;
        if (tau0 + tl >= TAU - 16) acc += s;
    }
    m_state[idx] = m;
    s_state[idx] = s;
    if (last) out[idx] = acc;
}

extern "C" void kernel_launch(void* const* d_in, const int* in_sizes, int n_in,
                              void* d_out, int out_size, void* d_ws, size_t ws_size,
                              hipStream_t stream)
{
    const float* x     = (const float*)d_in[0];   // [B][T][IN]
    const float* fc1_w = (const float*)d_in[1];   // [HID][IN]
    const float* fc1_b = (const float*)d_in[2];   // [HID]
    const float* fc2_w = (const float*)d_in[3];   // [OUT][HID]
    const float* fc2_b = (const float*)d_in[4];   // [OUT]
    float* out = (float*)d_out;                   // [B][OUT]

    char* ws = (char*)d_ws;
    size_t off = 0;
    float* Z1 = (float*)(ws + off);               off += (size_t)B * T * HID * 4;   // 16.8 MB
    unsigned long long* Sbits = (unsigned long long*)(ws + off);
                                                  off += (size_t)TAU * B * HID / 8; //  8.4 MB
    float* Z2c = (float*)(ws + off);              off += (size_t)CHUNK * B * OUT * 4; // 33.5 MB
    float* m_state = (float*)(ws + off);          off += (size_t)B * OUT * 4;       //  0.5 MB
    float* s_state = (float*)(ws + off);          off += (size_t)B * OUT * 4;       //  0.5 MB
    // total ~59.8 MB

    // GEMM1: Z1[b*T+t][h] = x . fc1_w^T + fc1_b
    {
        dim3 grid(HID / 128, (B * T) / 128);
        gemm1_f32<<<grid, 256, 0, stream>>>(x, fc1_w, fc1_b, Z1, B * T, HID, IN);
    }
    // rec1: all 256 steps of layer-1, bit-packed spikes
    rec1<<<(B * HID) / 256, 256, 0, stream>>>(Z1, Sbits);

    // 4 chunks of (GEMM2, rec2)
    const unsigned char* Sbytes = (const unsigned char*)Sbits;
    for (int c = 0; c < TAU / CHUNK; ++c) {
        dim3 grid(OUT / 128, (CHUNK * B) / 128);
        gemm2_bits<<<grid, 256, 0, stream>>>(Sbytes, fc2_w, fc2_b, Z2c,
                                             c * CHUNK * B);
        rec2_chunk<<<(B * OUT) / 256, 256, 0, stream>>>(
            Z2c, m_state, s_state, out, c * CHUNK, (c == TAU / CHUNK - 1) ? 1 : 0);
    }
}

// Round 10
// 863.237 us; speedup vs baseline: 2.2857x; 2.2857x over previous
//
#include <hip/hip_runtime.h>
#include <hip/hip_bf16.h>

// SNN: B=128, T=16, IN=2048, HID=2048, OUT=1024; 256 total steps.
//   wsplit: W2 -> exact 3x bf16 split (hi/mid/lo), w == hi+mid+lo in fp32
//   Z1 = X @ W1^T + b1          (fp32 VALU GEMM, unchanged from R3)
//   rec1: layer-1 recurrence -> bit-packed spikes (8.4 MB)
//   per 64-step chunk: gemm2_mfma (bf16 MFMA, A=bits unpacked in-kernel,
//                      acc = sum over 3 W2 splits), then rec2 recurrence.
// ws layout (55.6 MB, aliasing Z1 under Z2c; proven budget 59.8 MB):
//   [0, 33.5M): Z1 (phase 1) / Z2c (chunk phase)   [33.5M: Sbits 8.4M]
//   [41.9M: W2h/W2m/W2l 3x4.2M]  [54.5M: m_state/s_state 1M]
constexpr int B   = 128;
constexpr int T   = 16;
constexpr int IN  = 2048;
constexpr int HID = 2048;
constexpr int OUT = 1024;
constexpr int TAU = 256;
constexpr int CHUNK = 64;
constexpr float DECAY  = 0.2f;
constexpr float THRESH = 0.5f;

typedef short  v8s  __attribute__((ext_vector_type(8)));
typedef float  f32x4 __attribute__((ext_vector_type(4)));

__device__ __forceinline__ float bf2f(unsigned short u) {
    union { unsigned int i; float f; } v; v.i = ((unsigned int)u) << 16; return v.f;
}
__device__ __forceinline__ unsigned short f2bf_rne(float f) {
    union { float f; unsigned int i; } v; v.f = f;
    return (unsigned short)((v.i + 0x7FFFu + ((v.i >> 16) & 1u)) >> 16);
}

// async global->LDS, 16B per lane. dest must be the wave-uniform base.
__device__ __forceinline__ void gload_lds16(const void* g, void* l) {
    __builtin_amdgcn_global_load_lds(
        (const __attribute__((address_space(1))) void*)g,
        (__attribute__((address_space(3))) void*)l, 16, 0, 0);
}

// ---------------- wsplit: fc2_w (fp32) -> exact hi+mid+lo bf16 -------------
__global__ __launch_bounds__(256)
void wsplit(const float* __restrict__ W, unsigned short* __restrict__ Wh,
            unsigned short* __restrict__ Wm, unsigned short* __restrict__ Wl)
{
    int i = blockIdx.x * 256 + threadIdx.x;           // 4 elements per thread
    float4 w = *(const float4*)(W + (size_t)i * 4);
    float wv[4] = { w.x, w.y, w.z, w.w };
    unsigned short h[4], m[4], lo[4];
    #pragma unroll
    for (int j = 0; j < 4; j++) {
        h[j]  = f2bf_rne(wv[j]);  float r1 = wv[j] - bf2f(h[j]);
        m[j]  = f2bf_rne(r1);     float r2 = r1 - bf2f(m[j]);
        lo[j] = f2bf_rne(r2);     // r2 has <=8 significant bits -> exact
    }
    *(ushort4*)(Wh + (size_t)i * 4) = make_ushort4(h[0], h[1], h[2], h[3]);
    *(ushort4*)(Wm + (size_t)i * 4) = make_ushort4(m[0], m[1], m[2], m[3]);
    *(ushort4*)(Wl + (size_t)i * 4) = make_ushort4(lo[0], lo[1], lo[2], lo[3]);
}

// ---------------- GEMM1: fp32 VALU (unchanged numerics from R3) ------------
__global__ __launch_bounds__(256)
void gemm1_f32(const float* __restrict__ A, const float* __restrict__ W,
               const float* __restrict__ bias, float* __restrict__ C,
               int M, int N, int K)
{
    __shared__ float As[8][128];
    __shared__ float Bs[8][128];
    const int tid = threadIdx.x;
    const int tx = tid & 15, ty = tid >> 4;
    const int row0 = blockIdx.y * 128, col0 = blockIdx.x * 128;

    float acc[8][8];
    #pragma unroll
    for (int i = 0; i < 8; i++)
        #pragma unroll
        for (int j = 0; j < 8; j++) acc[i][j] = 0.f;

    const int sr = tid >> 1;
    const int sk = (tid & 1) << 2;

    for (int k0 = 0; k0 < K; k0 += 8) {
        float4 av = *(const float4*)(A + (size_t)(row0 + sr) * K + (k0 + sk));
        float4 bv = *(const float4*)(W + (size_t)(col0 + sr) * K + (k0 + sk));
        __syncthreads();
        As[sk + 0][sr] = av.x; As[sk + 1][sr] = av.y;
        As[sk + 2][sr] = av.z; As[sk + 3][sr] = av.w;
        Bs[sk + 0][sr] = bv.x; Bs[sk + 1][sr] = bv.y;
        Bs[sk + 2][sr] = bv.z; Bs[sk + 3][sr] = bv.w;
        __syncthreads();
        #pragma unroll
        for (int k = 0; k < 8; k++) {
            float a[8], b[8];
            #pragma unroll
            for (int i = 0; i < 8; i++) a[i] = As[k][ty * 8 + i];
            #pragma unroll
            for (int j = 0; j < 8; j++) b[j] = Bs[k][tx * 8 + j];
            #pragma unroll
            for (int i = 0; i < 8; i++)
                #pragma unroll
                for (int j = 0; j < 8; j++)
                    acc[i][j] = fmaf(a[i], b[j], acc[i][j]);
        }
    }
    #pragma unroll
    for (int i = 0; i < 8; i++) {
        size_t r = (size_t)(row0 + ty * 8 + i);
        int c0 = col0 + tx * 8;
        float4 o0, o1;
        o0.x = acc[i][0] + bias[c0 + 0]; o0.y = acc[i][1] + bias[c0 + 1];
        o0.z = acc[i][2] + bias[c0 + 2]; o0.w = acc[i][3] + bias[c0 + 3];
        o1.x = acc[i][4] + bias[c0 + 4]; o1.y = acc[i][5] + bias[c0 + 5];
        o1.z = acc[i][6] + bias[c0 + 6]; o1.w = acc[i][7] + bias[c0 + 7];
        *(float4*)(C + r * N + c0)     = o0;
        *(float4*)(C + r * N + c0 + 4) = o1;
    }
}

// ---------------- rec1: layer-1 recurrence, bit-packed spikes --------------
__global__ __launch_bounds__(256)
void rec1(const float* __restrict__ Z1, unsigned long long* __restrict__ Sbits)
{
    int idx = blockIdx.x * 256 + threadIdx.x;   // b*HID + h
    int h = idx & (HID - 1);
    int b = idx >> 11;
    float z[16];
    #pragma unroll
    for (int t = 0; t < 16; t++)
        z[t] = Z1[((size_t)(b * T + t)) * HID + h];
    const size_t wbase = (size_t)b * (HID / 64) + (h >> 6);
    const bool lead = (threadIdx.x & 63) == 0;
    float m = 0.f, s = 0.f;
    for (int tau = 0; tau < TAU; ++tau) {
        m = m * DECAY * (1.f - s) + z[tau & 15];
        unsigned long long mask = __ballot(m > THRESH);
        s = (m > THRESH) ? 1.f : 0.f;
        if (lead)
            Sbits[(size_t)tau * (B * HID / 64) + wbase] = mask;
    }
}

// ---------------- GEMM2: bf16 MFMA, A = spike bits, B = 3-split W2 ---------
// Tile 128x128, 4 waves (2x2 of 64x64), BK=32, mfma_f32_16x16x32_bf16.
// LDS fragment-ordered: slot(g,s,r) 16B = rows/cols [g*16+r], k [k0+s*8..+7].
__global__ __launch_bounds__(256)
void gemm2_mfma(const unsigned char* __restrict__ Sbytes,   // [TAU*B][256] bits
                const unsigned short* __restrict__ W2h,
                const unsigned short* __restrict__ W2m,
                const unsigned short* __restrict__ W2l,
                const float* __restrict__ bias,
                float* __restrict__ C,                      // [CHUNK*B][OUT]
                int m0glob)
{
    __shared__ unsigned short As[4096];      //  8 KB: [8 g][4 s][16 r][8 bf16]
    __shared__ unsigned short Bs[3][4096];   // 24 KB: per split, same layout
    const int tid = threadIdx.x;
    const int l  = tid & 63, w = tid >> 6;
    const int wr = w >> 1, wc = w & 1;       // wave 2x2 grid
    const int lg = l >> 4, lr = l & 15;      // k-slot group / row-col in frag
    const int row0 = blockIdx.y * 128, col0 = blockIdx.x * 128;

    f32x4 acc[4][4];
    #pragma unroll
    for (int m = 0; m < 4; m++)
        #pragma unroll
        for (int n = 0; n < 4; n++) acc[m][n] = (f32x4){0.f, 0.f, 0.f, 0.f};

    // A staging (bit unpack): thread covers slots (g_a, s_lo) and (g_a, s_lo+1)
    const int g_a = tid >> 5, u = tid & 31;
    const int r_a = u & 15, s_lo = (u >> 4) << 1;            // 0 or 2
    const unsigned char* arow =
        Sbytes + (size_t)(m0glob + row0 + g_a * 16 + r_a) * 256 + s_lo;
    unsigned short* As_w0 = &As[(g_a * 64 + s_lo * 16 + r_a) * 8];
    unsigned short* As_w1 = &As[(g_a * 64 + (s_lo + 1) * 16 + r_a) * 8];

    // B staging: 2 x gload_lds16 per split per thread
    const int s_b = (tid >> 4) & 3, r_b = tid & 15;
    const size_t boff1 = (size_t)(col0 + w * 16 + r_b) * 2048 + s_b * 8;
    const size_t boff2 = (size_t)(col0 + (w + 4) * 16 + r_b) * 2048 + s_b * 8;
    unsigned short* bdst1 = &Bs[0][w * 512];          // wave-uniform bases
    unsigned short* bdst2 = &Bs[0][2048 + w * 512];

    for (int k0 = 0; k0 < HID; k0 += 32) {
        unsigned int bits = *(const unsigned short*)(arow + (k0 >> 3));
        __syncthreads();                       // prior reads done before overwrite
        gload_lds16(W2h + boff1 + k0, bdst1);
        gload_lds16(W2h + boff2 + k0, bdst2);
        gload_lds16(W2m + boff1 + k0, bdst1 + 4096);
        gload_lds16(W2m + boff2 + k0, bdst2 + 4096);
        gload_lds16(W2l + boff1 + k0, bdst1 + 8192);
        gload_lds16(W2l + boff2 + k0, bdst2 + 8192);
        // unpack 16 spike bits -> 16 bf16 (exact 0/1), 2x ds_write_b128
        unsigned int q[8];
        #pragma unroll
        for (int j = 0; j < 8; j++)
            q[j] = (((bits >> (2 * j)) & 1u) ? 0x3F80u : 0u) |
                   (((bits >> (2 * j + 1)) & 1u) ? 0x3F800000u : 0u);
        *(uint4*)As_w0 = make_uint4(q[0], q[1], q[2], q[3]);
        *(uint4*)As_w1 = make_uint4(q[4], q[5], q[6], q[7]);
        __syncthreads();                       // staging (vmcnt+lgkm) complete

        v8s a[4];
        #pragma unroll
        for (int m = 0; m < 4; m++)
            a[m] = *(const v8s*)&As[(((wr * 4 + m) * 4 + lg) * 16 + lr) * 8];
        #pragma unroll
        for (int sp = 0; sp < 3; sp++) {
            #pragma unroll
            for (int n = 0; n < 4; n++) {
                v8s b = *(const v8s*)&Bs[sp][(((wc * 4 + n) * 4 + lg) * 16 + lr) * 8];
                #pragma unroll
                for (int m = 0; m < 4; m++)
                    acc[m][n] = __builtin_amdgcn_mfma_f32_16x16x32_bf16(
                                    a[m], b, acc[m][n], 0, 0, 0);
            }
        }
    }

    // epilogue: C/D layout col=lane&15, row=(lane>>4)*4+q  [guide m89/m91]
    #pragma unroll
    for (int m = 0; m < 4; m++) {
        int row = row0 + wr * 64 + m * 16 + (lg << 2);
        #pragma unroll
        for (int n = 0; n < 4; n++) {
            int col = col0 + wc * 64 + n * 16 + lr;
            float bv = bias[col];
            #pragma unroll
            for (int q2 = 0; q2 < 4; q2++)
                C[(size_t)(row + q2) * OUT + col] = acc[m][n][q2] + bv;
        }
    }
}

// ---------------- rec2 chunk: layer-2 recurrence over 64 tau steps ---------
__global__ __launch_bounds__(256)
void rec2_chunk(const float* __restrict__ Z2c, float* __restrict__ m_state,
                float* __restrict__ s_state, float* __restrict__ out,
                int tau0, int last)
{
    int idx = blockIdx.x * 256 + threadIdx.x;   // b*OUT + o
    int o = idx & (OUT - 1);
    int b = idx >> 10;
    float m, s;
    if (tau0 == 0) { m = 0.f; s = 0.f; }
    else           { m = m_state[idx]; s = s_state[idx]; }
    float acc = 0.f;
    for (int tl = 0; tl < CHUNK; ++tl) {
        float zv = Z2c[((size_t)(tl * B + b)) * OUT + o];
        m = m * DECAY * (1.f - s) + zv;
        s = (m > THRESH) ? 1.f : 0.f;
        if (tau0 + tl >= TAU - 16) acc += s;
    }
    m_state[idx] = m;
    s_state[idx] = s;
    if (last) out[idx] = acc;
}

extern "C" void kernel_launch(void* const* d_in, const int* in_sizes, int n_in,
                              void* d_out, int out_size, void* d_ws, size_t ws_size,
                              hipStream_t stream)
{
    const float* x     = (const float*)d_in[0];
    const float* fc1_w = (const float*)d_in[1];
    const float* fc1_b = (const float*)d_in[2];
    const float* fc2_w = (const float*)d_in[3];
    const float* fc2_b = (const float*)d_in[4];
    float* out = (float*)d_out;

    char* ws = (char*)d_ws;
    float* Z1  = (float*)ws;                          // 16.8 MB, dead after rec1
    float* Z2c = (float*)ws;                          // 33.5 MB, chunk phase (alias)
    unsigned long long* Sbits = (unsigned long long*)(ws + 33554432);      // 8.4 MB
    unsigned short* W2h = (unsigned short*)(ws + 33554432 + 8388608);      // 4.2 MB
    unsigned short* W2m = W2h + (size_t)OUT * HID;                         // 4.2 MB
    unsigned short* W2l = W2m + (size_t)OUT * HID;                         // 4.2 MB
    float* m_state = (float*)(ws + 33554432 + 8388608 + 3 * 4194304);      // 0.5 MB
    float* s_state = m_state + B * OUT;                                    // 0.5 MB

    wsplit<<<(OUT * HID / 4) / 256, 256, 0, stream>>>(fc2_w, W2h, W2m, W2l);

    {
        dim3 grid(HID / 128, (B * T) / 128);
        gemm1_f32<<<grid, 256, 0, stream>>>(x, fc1_w, fc1_b, Z1, B * T, HID, IN);
    }
    rec1<<<(B * HID) / 256, 256, 0, stream>>>(Z1, Sbits);

    const unsigned char* Sbytes = (const unsigned char*)Sbits;
    for (int c = 0; c < TAU / CHUNK; ++c) {
        dim3 grid(OUT / 128, (CHUNK * B) / 128);
        gemm2_mfma<<<grid, 256, 0, stream>>>(Sbytes, W2h, W2m, W2l, fc2_b, Z2c,
                                             c * CHUNK * B);
        rec2_chunk<<<(B * OUT) / 256, 256, 0, stream>>>(
            Z2c, m_state, s_state, out, c * CHUNK, (c == TAU / CHUNK - 1) ? 1 : 0);
    }
}

// Round 11
// 818.507 us; speedup vs baseline: 2.4107x; 1.0546x over previous
//
#include <hip/hip_runtime.h>
#include <hip/hip_bf16.h>

// SNN: B=128, T=16, IN=2048, HID=2048, OUT=1024; 256 total steps.
//   wsplit: W2 -> exact 3x bf16 split (hi/mid/lo), w == hi+mid+lo in fp32
//   Z1 = X @ W1^T + b1          (fp32 VALU GEMM, 64x64 tiles v2: 4 blocks/CU)
//   rec1: layer-1 recurrence -> bit-packed spikes (8.4 MB)
//   per 64-step chunk: gemm2_mfma (bf16 MFMA, A=bits unpacked in-kernel,
//                      acc = sum over 3 W2 splits), then rec2 recurrence.
// ws layout (55.6 MB, aliasing Z1 under Z2c; proven budget 59.8 MB).
constexpr int B   = 128;
constexpr int T   = 16;
constexpr int IN  = 2048;
constexpr int HID = 2048;
constexpr int OUT = 1024;
constexpr int TAU = 256;
constexpr int CHUNK = 64;
constexpr float DECAY  = 0.2f;
constexpr float THRESH = 0.5f;

typedef short  v8s  __attribute__((ext_vector_type(8)));
typedef float  f32x4 __attribute__((ext_vector_type(4)));

__device__ __forceinline__ float bf2f(unsigned short u) {
    union { unsigned int i; float f; } v; v.i = ((unsigned int)u) << 16; return v.f;
}
__device__ __forceinline__ unsigned short f2bf_rne(float f) {
    union { float f; unsigned int i; } v; v.f = f;
    return (unsigned short)((v.i + 0x7FFFu + ((v.i >> 16) & 1u)) >> 16);
}

// async global->LDS, 16B per lane. dest must be the wave-uniform base.
__device__ __forceinline__ void gload_lds16(const void* g, void* l) {
    __builtin_amdgcn_global_load_lds(
        (const __attribute__((address_space(1))) void*)g,
        (__attribute__((address_space(3))) void*)l, 16, 0, 0);
}

// ---------------- wsplit: fc2_w (fp32) -> exact hi+mid+lo bf16 -------------
__global__ __launch_bounds__(256)
void wsplit(const float* __restrict__ W, unsigned short* __restrict__ Wh,
            unsigned short* __restrict__ Wm, unsigned short* __restrict__ Wl)
{
    int i = blockIdx.x * 256 + threadIdx.x;           // 4 elements per thread
    float4 w = *(const float4*)(W + (size_t)i * 4);
    float wv[4] = { w.x, w.y, w.z, w.w };
    unsigned short h[4], m[4], lo[4];
    #pragma unroll
    for (int j = 0; j < 4; j++) {
        h[j]  = f2bf_rne(wv[j]);  float r1 = wv[j] - bf2f(h[j]);
        m[j]  = f2bf_rne(r1);     float r2 = r1 - bf2f(m[j]);
        lo[j] = f2bf_rne(r2);     // r2 has <=8 significant bits -> exact
    }
    *(ushort4*)(Wh + (size_t)i * 4) = make_ushort4(h[0], h[1], h[2], h[3]);
    *(ushort4*)(Wm + (size_t)i * 4) = make_ushort4(m[0], m[1], m[2], m[3]);
    *(ushort4*)(Wl + (size_t)i * 4) = make_ushort4(lo[0], lo[1], lo[2], lo[3]);
}

// ---------------- GEMM1 v2: fp32 VALU, 64x64 tile, 4 blocks/CU -------------
// C[M][N] = A[M][K] @ W[N][K]^T + bias. BK=16, 256 thr, 4x4 micro-tile.
// Per-output k-order is strictly ascending -> Z1 bit-identical to the
// 128x128/BK=8 version (R3/R10, absmax 0.0). LDS padded [16][68]: no staging
// write conflicts, 16B-aligned rows for b128 reads.
__global__ __launch_bounds__(256, 4)
void gemm1_f32v2(const float* __restrict__ A, const float* __restrict__ W,
                 const float* __restrict__ bias, float* __restrict__ C,
                 int M, int N, int K)
{
    __shared__ float As[16][68];
    __shared__ float Bs[16][68];
    const int tid = threadIdx.x;
    const int tx = tid & 15, ty = tid >> 4;
    const int row0 = blockIdx.y * 64, col0 = blockIdx.x * 64;

    float acc[4][4];
    #pragma unroll
    for (int i = 0; i < 4; i++)
        #pragma unroll
        for (int j = 0; j < 4; j++) acc[i][j] = 0.f;

    const int sr = tid >> 2;          // 0..63 tile row
    const int sk = (tid & 3) << 2;    // 0,4,8,12

    for (int k0 = 0; k0 < K; k0 += 16) {
        float4 av = *(const float4*)(A + (size_t)(row0 + sr) * K + (k0 + sk));
        float4 bv = *(const float4*)(W + (size_t)(col0 + sr) * K + (k0 + sk));
        __syncthreads();
        As[sk + 0][sr] = av.x; As[sk + 1][sr] = av.y;
        As[sk + 2][sr] = av.z; As[sk + 3][sr] = av.w;
        Bs[sk + 0][sr] = bv.x; Bs[sk + 1][sr] = bv.y;
        Bs[sk + 2][sr] = bv.z; Bs[sk + 3][sr] = bv.w;
        __syncthreads();
        #pragma unroll
        for (int k = 0; k < 16; k++) {
            float4 a = *(const float4*)&As[k][ty * 4];
            float4 b = *(const float4*)&Bs[k][tx * 4];
            float ar[4] = { a.x, a.y, a.z, a.w };
            float br[4] = { b.x, b.y, b.z, b.w };
            #pragma unroll
            for (int i = 0; i < 4; i++)
                #pragma unroll
                for (int j = 0; j < 4; j++)
                    acc[i][j] = fmaf(ar[i], br[j], acc[i][j]);
        }
    }
    #pragma unroll
    for (int i = 0; i < 4; i++) {
        size_t r = (size_t)(row0 + ty * 4 + i);
        int c0 = col0 + tx * 4;
        float4 o;
        o.x = acc[i][0] + bias[c0 + 0];
        o.y = acc[i][1] + bias[c0 + 1];
        o.z = acc[i][2] + bias[c0 + 2];
        o.w = acc[i][3] + bias[c0 + 3];
        *(float4*)(C + r * N + c0) = o;
    }
}

// ---------------- rec1: layer-1 recurrence, bit-packed spikes --------------
__global__ __launch_bounds__(256)
void rec1(const float* __restrict__ Z1, unsigned long long* __restrict__ Sbits)
{
    int idx = blockIdx.x * 256 + threadIdx.x;   // b*HID + h
    int h = idx & (HID - 1);
    int b = idx >> 11;
    float z[16];
    #pragma unroll
    for (int t = 0; t < 16; t++)
        z[t] = Z1[((size_t)(b * T + t)) * HID + h];
    const size_t wbase = (size_t)b * (HID / 64) + (h >> 6);
    const bool lead = (threadIdx.x & 63) == 0;
    float m = 0.f, s = 0.f;
    for (int tau = 0; tau < TAU; ++tau) {
        m = m * DECAY * (1.f - s) + z[tau & 15];
        unsigned long long mask = __ballot(m > THRESH);
        s = (m > THRESH) ? 1.f : 0.f;
        if (lead)
            Sbits[(size_t)tau * (B * HID / 64) + wbase] = mask;
    }
}

// ---------------- GEMM2: bf16 MFMA, A = spike bits, B = 3-split W2 ---------
// Tile 128x128, 4 waves (2x2 of 64x64), BK=32, mfma_f32_16x16x32_bf16.
// LDS fragment-ordered: slot(g,s,r) 16B = rows/cols [g*16+r], k [k0+s*8..+7].
__global__ __launch_bounds__(256)
void gemm2_mfma(const unsigned char* __restrict__ Sbytes,   // [TAU*B][256] bits
                const unsigned short* __restrict__ W2h,
                const unsigned short* __restrict__ W2m,
                const unsigned short* __restrict__ W2l,
                const float* __restrict__ bias,
                float* __restrict__ C,                      // [CHUNK*B][OUT]
                int m0glob)
{
    __shared__ unsigned short As[4096];      //  8 KB: [8 g][4 s][16 r][8 bf16]
    __shared__ unsigned short Bs[3][4096];   // 24 KB: per split, same layout
    const int tid = threadIdx.x;
    const int l  = tid & 63, w = tid >> 6;
    const int wr = w >> 1, wc = w & 1;       // wave 2x2 grid
    const int lg = l >> 4, lr = l & 15;      // k-slot group / row-col in frag
    const int row0 = blockIdx.y * 128, col0 = blockIdx.x * 128;

    f32x4 acc[4][4];
    #pragma unroll
    for (int m = 0; m < 4; m++)
        #pragma unroll
        for (int n = 0; n < 4; n++) acc[m][n] = (f32x4){0.f, 0.f, 0.f, 0.f};

    // A staging (bit unpack): thread covers slots (g_a, s_lo) and (g_a, s_lo+1)
    const int g_a = tid >> 5, u = tid & 31;
    const int r_a = u & 15, s_lo = (u >> 4) << 1;            // 0 or 2
    const unsigned char* arow =
        Sbytes + (size_t)(m0glob + row0 + g_a * 16 + r_a) * 256 + s_lo;
    unsigned short* As_w0 = &As[(g_a * 64 + s_lo * 16 + r_a) * 8];
    unsigned short* As_w1 = &As[(g_a * 64 + (s_lo + 1) * 16 + r_a) * 8];

    // B staging: 2 x gload_lds16 per split per thread
    const int s_b = (tid >> 4) & 3, r_b = tid & 15;
    const size_t boff1 = (size_t)(col0 + w * 16 + r_b) * 2048 + s_b * 8;
    const size_t boff2 = (size_t)(col0 + (w + 4) * 16 + r_b) * 2048 + s_b * 8;
    unsigned short* bdst1 = &Bs[0][w * 512];          // wave-uniform bases
    unsigned short* bdst2 = &Bs[0][2048 + w * 512];

    for (int k0 = 0; k0 < HID; k0 += 32) {
        unsigned int bits = *(const unsigned short*)(arow + (k0 >> 3));
        __syncthreads();                       // prior reads done before overwrite
        gload_lds16(W2h + boff1 + k0, bdst1);
        gload_lds16(W2h + boff2 + k0, bdst2);
        gload_lds16(W2m + boff1 + k0, bdst1 + 4096);
        gload_lds16(W2m + boff2 + k0, bdst2 + 4096);
        gload_lds16(W2l + boff1 + k0, bdst1 + 8192);
        gload_lds16(W2l + boff2 + k0, bdst2 + 8192);
        // unpack 16 spike bits -> 16 bf16 (exact 0/1), 2x ds_write_b128
        unsigned int q[8];
        #pragma unroll
        for (int j = 0; j < 8; j++)
            q[j] = (((bits >> (2 * j)) & 1u) ? 0x3F80u : 0u) |
                   (((bits >> (2 * j + 1)) & 1u) ? 0x3F800000u : 0u);
        *(uint4*)As_w0 = make_uint4(q[0], q[1], q[2], q[3]);
        *(uint4*)As_w1 = make_uint4(q[4], q[5], q[6], q[7]);
        __syncthreads();                       // staging (vmcnt+lgkm) complete

        v8s a[4];
        #pragma unroll
        for (int m = 0; m < 4; m++)
            a[m] = *(const v8s*)&As[(((wr * 4 + m) * 4 + lg) * 16 + lr) * 8];
        #pragma unroll
        for (int sp = 0; sp < 3; sp++) {
            #pragma unroll
            for (int n = 0; n < 4; n++) {
                v8s b = *(const v8s*)&Bs[sp][(((wc * 4 + n) * 4 + lg) * 16 + lr) * 8];
                #pragma unroll
                for (int m = 0; m < 4; m++)
                    acc[m][n] = __builtin_amdgcn_mfma_f32_16x16x32_bf16(
                                    a[m], b, acc[m][n], 0, 0, 0);
            }
        }
    }

    // epilogue: C/D layout col=lane&15, row=(lane>>4)*4+q  [guide m89/m91]
    #pragma unroll
    for (int m = 0; m < 4; m++) {
        int row = row0 + wr * 64 + m * 16 + (lg << 2);
        #pragma unroll
        for (int n = 0; n < 4; n++) {
            int col = col0 + wc * 64 + n * 16 + lr;
            float bv = bias[col];
            #pragma unroll
            for (int q2 = 0; q2 < 4; q2++)
                C[(size_t)(row + q2) * OUT + col] = acc[m][n][q2] + bv;
        }
    }
}

// ---------------- rec2 chunk: layer-2 recurrence over 64 tau steps ---------
__global__ __launch_bounds__(256)
void rec2_chunk(const float* __restrict__ Z2c, float* __restrict__ m_state,
                float* __restrict__ s_state, float* __restrict__ out,
                int tau0, int last)
{
    int idx = blockIdx.x * 256 + threadIdx.x;   // b*OUT + o
    int o = idx & (OUT - 1);
    int b = idx >> 10;
    float m, s;
    if (tau0 == 0) { m = 0.f; s = 0.f; }
    else           { m = m_state[idx]; s = s_state[idx]; }
    float acc = 0.f;
    for (int tl = 0; tl < CHUNK; ++tl) {
        float zv = Z2c[((size_t)(tl * B + b)) * OUT + o];
        m = m * DECAY * (1.f - s) + zv;
        s = (m > THRESH) ? 1.f : 0.f;
        if (tau0 + tl >= TAU - 16) acc += s;
    }
    m_state[idx] = m;
    s_state[idx] = s;
    if (last) out[idx] = acc;
}

extern "C" void kernel_launch(void* const* d_in, const int* in_sizes, int n_in,
                              void* d_out, int out_size, void* d_ws, size_t ws_size,
                              hipStream_t stream)
{
    const float* x     = (const float*)d_in[0];
    const float* fc1_w = (const float*)d_in[1];
    const float* fc1_b = (const float*)d_in[2];
    const float* fc2_w = (const float*)d_in[3];
    const float* fc2_b = (const float*)d_in[4];
    float* out = (float*)d_out;

    char* ws = (char*)d_ws;
    float* Z1  = (float*)ws;                          // 16.8 MB, dead after rec1
    float* Z2c = (float*)ws;                          // 33.5 MB, chunk phase (alias)
    unsigned long long* Sbits = (unsigned long long*)(ws + 33554432);      // 8.4 MB
    unsigned short* W2h = (unsigned short*)(ws + 33554432 + 8388608);      // 4.2 MB
    unsigned short* W2m = W2h + (size_t)OUT * HID;                         // 4.2 MB
    unsigned short* W2l = W2m + (size_t)OUT * HID;                         // 4.2 MB
    float* m_state = (float*)(ws + 33554432 + 8388608 + 3 * 4194304);      // 0.5 MB
    float* s_state = m_state + B * OUT;                                    // 0.5 MB

    wsplit<<<(OUT * HID / 4) / 256, 256, 0, stream>>>(fc2_w, W2h, W2m, W2l);

    // GEMM1 v2: 64x64 tiles -> 1024 blocks (4/CU), bit-identical Z1
    {
        dim3 grid(HID / 64, (B * T) / 64);
        gemm1_f32v2<<<grid, 256, 0, stream>>>(x, fc1_w, fc1_b, Z1, B * T, HID, IN);
    }
    rec1<<<(B * HID) / 256, 256, 0, stream>>>(Z1, Sbits);

    const unsigned char* Sbytes = (const unsigned char*)Sbits;
    for (int c = 0; c < TAU / CHUNK; ++c) {
        dim3 grid(OUT / 128, (CHUNK * B) / 128);
        gemm2_mfma<<<grid, 256, 0, stream>>>(Sbytes, W2h, W2m, W2l, fc2_b, Z2c,
                                             c * CHUNK * B);
        rec2_chunk<<<(B * OUT) / 256, 256, 0, stream>>>(
            Z2c, m_state, s_state, out, c * CHUNK, (c == TAU / CHUNK - 1) ? 1 : 0);
    }
}